// Round 6
// baseline (581.648 us; speedup 1.0000x reference)
//
#include <hip/hip_runtime.h>

#define N_NODES 100000
#define N_EDGES 1250000
#define FEAT 64
#define N_GRAPHS 64
#define SLOT_MAIN 16
#define SLOT_OVF 32
#define MAXDEG 48     // SLOT_MAIN + SLOT_OVF
#define NRANGE 8      // dst ranges, one per XCD (blockIdx%8 -> XCD round-robin)
#define RANGE_SZ (N_NODES / NRANGE)  // 12500
#define TILE 64
#define LDS_PITCH 65  // +1 pad: conflict-free row AND column access
#define N_TILES ((N_NODES + TILE - 1) / TILE)

// ---------------------------------------------------------------------------
// Transpose the four 64x64 weight matrices: WT[m][j][k] = W_m[k][j]
// ---------------------------------------------------------------------------
__global__ void transpose4_kernel(const float* __restrict__ W1_0,
                                  const float* __restrict__ W2_0,
                                  const float* __restrict__ W1_1,
                                  const float* __restrict__ W2_1,
                                  float* __restrict__ WT) {
  const int m = blockIdx.x >> 6;   // 0..3
  const int j = blockIdx.x & 63;
  const int k = threadIdx.x;
  const float* W = (m == 0) ? W1_0 : (m == 1) ? W2_0 : (m == 2) ? W1_1 : W2_1;
  WT[(m * FEAT + j) * FEAT + k] = W[k * FEAT + j];
}

// ---------------------------------------------------------------------------
// Build per-destination edge buckets, XCD-affine: blocks with blockIdx%8==r
// only process dst in range r, so each slot/deg cache line is written by a
// single XCD's L2 and written back once instead of ~once-per-store.
// ---------------------------------------------------------------------------
__global__ void hist_place_kernel(const int* __restrict__ src,
                                  const int* __restrict__ dst,
                                  int* __restrict__ deg,
                                  int* __restrict__ slots16,
                                  int* __restrict__ slots_ovf) {
  const int r   = blockIdx.x & (NRANGE - 1);
  const int ch  = blockIdx.x >> 3;
  const int nch = gridDim.x >> 3;
  const int lo  = r * RANGE_SZ;
  const int eper = (N_EDGES + nch - 1) / nch;
  const int e0 = ch * eper;
  const int e1 = min(e0 + eper, N_EDGES);
  for (int e = e0 + (int)threadIdx.x; e < e1; e += blockDim.x) {
    const int d = dst[e];
    if ((unsigned)(d - lo) < (unsigned)RANGE_SZ) {
      const int s = src[e];
      const int pos = atomicAdd(&deg[d], 1);
      if (pos < SLOT_MAIN)   slots16[(d << 4) + pos] = s;
      else if (pos < MAXDEG) slots_ovf[d * SLOT_OVF + (pos - SLOT_MAIN)] = s;
    }
  }
}

// ---------------------------------------------------------------------------
// Fused GIN layer, 64-node tile per block (4 waves).
// Phase 1 (lane=feat): each wave gathers 16 nodes (self + up to 48 neighbors),
//   writes summed rows to LDS atile[64][65].
// Phase 2/3 (lane=node): each lane holds its node's row in 64 VGPRs; wave w
//   computes output features j in [16w,16w+16). W^T rows are wave-uniform ->
//   s_loads; each output is 64 v_fmac(vgpr,sgpr) — no readlane.
// Phase 4 (lane=feat): pool into per-graph sums (batch sorted) or store rows.
// ---------------------------------------------------------------------------
template <bool POOL>
__global__ __launch_bounds__(256) void gin_layer_kernel(
    const float* __restrict__ hin,
    const int* __restrict__ deg,
    const int* __restrict__ slots16,
    const int* __restrict__ slots_ovf,
    const float* __restrict__ W1T, const float* __restrict__ b1,
    const float* __restrict__ W2T, const float* __restrict__ b2,
    float* __restrict__ hout,
    const int* __restrict__ batch,
    float* __restrict__ sums) {
  __shared__ float atile[TILE][LDS_PITCH];
  __shared__ float htile[TILE][LDS_PITCH];

  const int lane  = threadIdx.x & 63;
  const int w     = threadIdx.x >> 6;      // wave 0..3
  const int nbase = blockIdx.x * TILE;

  // ---- phase 1: gather ----
  for (int i = 0; i < 16; ++i) {
    const int n = nbase + w * 16 + i;      // wave-uniform
    if (n < N_NODES) {
      const int c  = min(deg[n], MAXDEG);
      const int cm = min(c, SLOT_MAIN);
      const int* sl = slots16 + (n << 4);
      int sidx[SLOT_MAIN];
#pragma unroll
      for (int ii = 0; ii < SLOT_MAIN; ++ii) sidx[ii] = sl[ii];

      float a = hin[(size_t)n * FEAT + lane];
      float v[SLOT_MAIN];
#pragma unroll
      for (int ii = 0; ii < SLOT_MAIN; ++ii)
        v[ii] = hin[(size_t)sidx[ii] * FEAT + lane];
#pragma unroll
      for (int ii = 0; ii < SLOT_MAIN; ++ii)
        a += (ii < cm) ? v[ii] : 0.0f;

      if (c > SLOT_MAIN) {
        const int* so = slots_ovf + (size_t)n * SLOT_OVF;
        for (int ii = SLOT_MAIN; ii < c; ++ii)
          a += hin[(size_t)so[ii - SLOT_MAIN] * FEAT + lane];
      }
      atile[w * 16 + i][lane] = a;
    }
  }
  __syncthreads();

  const int jbase = __builtin_amdgcn_readfirstlane(w * 16);

  // ---- phase 2: layer 1 (lane = node) ----
  {
    float ar[FEAT];
#pragma unroll
    for (int k = 0; k < FEAT; ++k) ar[k] = atile[lane][k];
#pragma unroll 4
    for (int jj = 0; jj < 16; ++jj) {
      const int j = jbase + jj;
      const float* __restrict__ wrow = W1T + j * FEAT;   // wave-uniform -> s_load
      float acc = b1[j];
#pragma unroll
      for (int k = 0; k < FEAT; ++k) acc = fmaf(ar[k], wrow[k], acc);
      htile[lane][j] = fmaxf(acc, 0.0f);
    }
  }
  __syncthreads();

  // ---- phase 3: layer 2 (lane = node), write h2 back into atile ----
  {
    float ar[FEAT];
#pragma unroll
    for (int k = 0; k < FEAT; ++k) ar[k] = htile[lane][k];
#pragma unroll 4
    for (int jj = 0; jj < 16; ++jj) {
      const int j = jbase + jj;
      const float* __restrict__ wrow = W2T + j * FEAT;
      float acc = b2[j];
#pragma unroll
      for (int k = 0; k < FEAT; ++k) acc = fmaf(ar[k], wrow[k], acc);
      atile[lane][j] = fmaxf(acc, 0.0f);
    }
  }
  __syncthreads();

  // ---- phase 4: output (lane = feat) ----
  if (POOL) {
    int curg = -1;
    float gacc = 0.0f;
    for (int i = 0; i < 16; ++i) {
      const int n = nbase + w * 16 + i;
      if (n >= N_NODES) break;
      const float hv = atile[w * 16 + i][lane];
      const int g = batch[n];                 // wave-uniform
      if (g != curg) {
        if (curg >= 0) atomicAdd(&sums[curg * FEAT + lane], gacc);
        curg = g;
        gacc = 0.0f;
      }
      gacc += hv;
    }
    if (curg >= 0) atomicAdd(&sums[curg * FEAT + lane], gacc);
  } else {
    for (int i = 0; i < 16; ++i) {
      const int n = nbase + w * 16 + i;
      if (n >= N_NODES) break;
      hout[(size_t)n * FEAT + lane] = atile[w * 16 + i][lane];
    }
  }
}

// ---------------------------------------------------------------------------
// out[g] = dot(sums[g,:], fcW) / cnt[g] + fcb; cnt via binary search on the
// sorted batch array.
// ---------------------------------------------------------------------------
__device__ __forceinline__ int lower_bound_dev(const int* __restrict__ a,
                                               int n, int key) {
  int lo = 0, hi = n;
  while (lo < hi) {
    const int mid = (lo + hi) >> 1;
    if (a[mid] < key) lo = mid + 1; else hi = mid;
  }
  return lo;
}

__global__ void finish_kernel(const float* __restrict__ sums,
                              const int* __restrict__ batch,
                              const float* __restrict__ fcW,
                              const float* __restrict__ fcb,
                              float* __restrict__ out) {
  const int g = blockIdx.x;
  const int lane = threadIdx.x;

  int cnt = 0;
  if (lane == 0) {
    const int lo = lower_bound_dev(batch, N_NODES, g);
    const int hi = lower_bound_dev(batch, N_NODES, g + 1);
    cnt = hi - lo;
  }
  cnt = __shfl(cnt, 0);

  float v = sums[g * FEAT + lane] * fcW[lane];
#pragma unroll
  for (int off = 32; off > 0; off >>= 1) v += __shfl_down(v, off);
  if (lane == 0) out[g] = v / fmaxf((float)cnt, 1.0f) + fcb[0];
}

extern "C" void kernel_launch(void* const* d_in, const int* in_sizes, int n_in,
                              void* d_out, int out_size, void* d_ws, size_t ws_size,
                              hipStream_t stream) {
  const float* x     = (const float*)d_in[0];
  const int*   ei    = (const int*)d_in[1];
  const int*   batch = (const int*)d_in[2];
  const float* W1_0  = (const float*)d_in[3];
  const float* b1_0  = (const float*)d_in[4];
  const float* W2_0  = (const float*)d_in[5];
  const float* b2_0  = (const float*)d_in[6];
  const float* W1_1  = (const float*)d_in[7];
  const float* b1_1  = (const float*)d_in[8];
  const float* W2_1  = (const float*)d_in[9];
  const float* b2_1  = (const float*)d_in[10];
  const float* fcW   = (const float*)d_in[11];
  const float* fcb   = (const float*)d_in[12];
  float* out = (float*)d_out;

  const int* src = ei;            // edge_index[0]
  const int* dst = ei + N_EDGES;  // edge_index[1]

  // workspace layout: [deg | sums | slots16 | slots_ovf | h1 | WT]
  int*   deg       = (int*)d_ws;                            // N_NODES
  float* sums      = (float*)(deg + N_NODES);               // N_GRAPHS*FEAT
  int*   slots16   = (int*)(sums + N_GRAPHS * FEAT);        // N_NODES*16
  int*   slots_ovf = slots16 + (size_t)N_NODES * SLOT_MAIN; // N_NODES*32
  float* h1        = (float*)(slots_ovf + (size_t)N_NODES * SLOT_OVF); // N_NODES*FEAT
  float* wt        = h1 + (size_t)N_NODES * FEAT;           // 4*FEAT*FEAT
  float* W1_0T = wt;
  float* W2_0T = wt + FEAT * FEAT;
  float* W1_1T = wt + 2 * FEAT * FEAT;
  float* W2_1T = wt + 3 * FEAT * FEAT;

  transpose4_kernel<<<4 * FEAT, FEAT, 0, stream>>>(W1_0, W2_0, W1_1, W2_1, wt);

  // zero deg + sums + slots16 in one contiguous memset
  hipMemsetAsync(deg, 0,
                 (size_t)(N_NODES + N_GRAPHS * FEAT + N_NODES * SLOT_MAIN) * sizeof(int),
                 stream);

  hist_place_kernel<<<NRANGE * 256, 256, 0, stream>>>(src, dst, deg, slots16, slots_ovf);

  gin_layer_kernel<false><<<N_TILES, 256, 0, stream>>>(x, deg, slots16, slots_ovf,
                                                       W1_0T, b1_0, W2_0T, b2_0,
                                                       h1, nullptr, nullptr);
  gin_layer_kernel<true><<<N_TILES, 256, 0, stream>>>(h1, deg, slots16, slots_ovf,
                                                      W1_1T, b1_1, W2_1T, b2_1,
                                                      nullptr, batch, sums);

  finish_kernel<<<N_GRAPHS, 64, 0, stream>>>(sums, batch, fcW, fcb, out);
}

// Round 8
// 348.431 us; speedup vs baseline: 1.6693x; 1.6693x over previous
//
#include <hip/hip_runtime.h>

#define N_NODES 100000
#define N_EDGES 1250000
#define FEAT 64
#define N_GRAPHS 64
#define SLOT_MAIN 16
#define SLOT_OVF 32
#define MAXDEG 48     // SLOT_MAIN + SLOT_OVF
#define NRANGE 8      // dst ranges, one per XCD (blockIdx%8 -> XCD round-robin)
#define RANGE_SZ (N_NODES / NRANGE)  // 12500

// ---------------------------------------------------------------------------
// Build per-destination edge buckets, XCD-affine: blocks with blockIdx%8==r
// only process dst in range r, so each slot/deg cache line is written by a
// single XCD's L2 and written back once instead of ~once-per-store.
// ---------------------------------------------------------------------------
__global__ void hist_place_kernel(const int* __restrict__ src,
                                  const int* __restrict__ dst,
                                  int* __restrict__ deg,
                                  int* __restrict__ slots16,
                                  int* __restrict__ slots_ovf) {
  const int r   = blockIdx.x & (NRANGE - 1);
  const int ch  = blockIdx.x >> 3;
  const int nch = gridDim.x >> 3;
  const int lo  = r * RANGE_SZ;
  const int eper = (N_EDGES + nch - 1) / nch;
  const int e0 = ch * eper;
  const int e1 = min(e0 + eper, N_EDGES);
  for (int e = e0 + (int)threadIdx.x; e < e1; e += blockDim.x) {
    const int d = dst[e];
    if ((unsigned)(d - lo) < (unsigned)RANGE_SZ) {
      const int s = src[e];
      const int pos = atomicAdd(&deg[d], 1);
      if (pos < SLOT_MAIN)   slots16[(d << 4) + pos] = s;
      else if (pos < MAXDEG) slots_ovf[d * SLOT_OVF + (pos - SLOT_MAIN)] = s;
    }
  }
}

__device__ __forceinline__ float bcast(float x, int k) {
  return __int_as_float(__builtin_amdgcn_readlane(__float_as_int(x), k));
}

// ---------------------------------------------------------------------------
// Fused GIN layer (round-5 structure + 2-node interleave). Wave per node pair,
// lane = output feature. 34 gather loads in flight per iteration; MLP with 4
// independent FMA chains (2 per node) sharing each weight value. No LDS, no
// barriers.
// ---------------------------------------------------------------------------
template <bool POOL>
__global__ __launch_bounds__(256) void gin_layer_kernel(
    const float* __restrict__ hin,
    const int* __restrict__ deg,
    const int* __restrict__ slots16,
    const int* __restrict__ slots_ovf,
    const float* __restrict__ W1, const float* __restrict__ b1,
    const float* __restrict__ W2, const float* __restrict__ b2,
    float* __restrict__ hout,
    const int* __restrict__ batch,
    float* __restrict__ sums) {
  const int lane = threadIdx.x & 63;
  int wid = blockIdx.x * (blockDim.x >> 6) + (threadIdx.x >> 6);
  wid = __builtin_amdgcn_readfirstlane(wid);
  const int nw = gridDim.x * (blockDim.x >> 6);

  float w1[FEAT], w2[FEAT];
#pragma unroll
  for (int k = 0; k < FEAT; ++k) w1[k] = W1[k * FEAT + lane];
#pragma unroll
  for (int k = 0; k < FEAT; ++k) w2[k] = W2[k * FEAT + lane];
  const float bb1 = b1[lane];
  const float bb2 = b2[lane];

  // even chunk so pairs never split (N_NODES even -> every pair complete)
  int chunk = (N_NODES + nw - 1) / nw;
  chunk = (chunk + 1) & ~1;
  const int n0 = wid * chunk;
  const int n1 = min(n0 + chunk, N_NODES);

  int curg = -1;
  float gacc = 0.0f;

  for (int n = n0; n < n1; n += 2) {
    const bool hasB = (n + 1 < n1);          // wave-uniform
    const int nA = n;
    const int nB = hasB ? n + 1 : n;

    const int cA  = min(deg[nA], MAXDEG);
    const int cB  = min(deg[nB], MAXDEG);
    const int cmA = min(cA, SLOT_MAIN);
    const int cmB = min(cB, SLOT_MAIN);

    const int* slA = slots16 + (nA << 4);
    const int* slB = slots16 + (nB << 4);
    int sA[SLOT_MAIN], sB[SLOT_MAIN];
#pragma unroll
    for (int i = 0; i < SLOT_MAIN; ++i) sA[i] = slA[i];
#pragma unroll
    for (int i = 0; i < SLOT_MAIN; ++i) sB[i] = slB[i];

    // 34 independent loads in flight
    float aA = hin[(size_t)nA * FEAT + lane];
    float aB = hin[(size_t)nB * FEAT + lane];
    float vA[SLOT_MAIN], vB[SLOT_MAIN];
#pragma unroll
    for (int i = 0; i < SLOT_MAIN; ++i) vA[i] = hin[(size_t)sA[i] * FEAT + lane];
#pragma unroll
    for (int i = 0; i < SLOT_MAIN; ++i) vB[i] = hin[(size_t)sB[i] * FEAT + lane];
#pragma unroll
    for (int i = 0; i < SLOT_MAIN; ++i) aA += (i < cmA) ? vA[i] : 0.0f;
#pragma unroll
    for (int i = 0; i < SLOT_MAIN; ++i) aB += (i < cmB) ? vB[i] : 0.0f;

    if (cA > SLOT_MAIN) {                    // uniform branch, ~12% of nodes
      const int* so = slots_ovf + (size_t)nA * SLOT_OVF;
      for (int i = SLOT_MAIN; i < cA; ++i)
        aA += hin[(size_t)so[i - SLOT_MAIN] * FEAT + lane];
    }
    if (hasB && cB > SLOT_MAIN) {
      const int* so = slots_ovf + (size_t)nB * SLOT_OVF;
      for (int i = SLOT_MAIN; i < cB; ++i)
        aB += hin[(size_t)so[i - SLOT_MAIN] * FEAT + lane];
    }

    // ---- MLP layer 1: 4 chains, weights shared across A/B ----
    float a0 = bb1, a1 = 0.0f, p0 = bb1, p1 = 0.0f;
#pragma unroll
    for (int k = 0; k < FEAT; k += 2) {
      const float wk0 = w1[k], wk1 = w1[k + 1];
      a0 = fmaf(bcast(aA, k),     wk0, a0);
      a1 = fmaf(bcast(aA, k + 1), wk1, a1);
      p0 = fmaf(bcast(aB, k),     wk0, p0);
      p1 = fmaf(bcast(aB, k + 1), wk1, p1);
    }
    const float h1A = fmaxf(a0 + a1, 0.0f);
    const float h1B = fmaxf(p0 + p1, 0.0f);

    // ---- MLP layer 2 ----
    float c0 = bb2, c1 = 0.0f, q0 = bb2, q1 = 0.0f;
#pragma unroll
    for (int k = 0; k < FEAT; k += 2) {
      const float wk0 = w2[k], wk1 = w2[k + 1];
      c0 = fmaf(bcast(h1A, k),     wk0, c0);
      c1 = fmaf(bcast(h1A, k + 1), wk1, c1);
      q0 = fmaf(bcast(h1B, k),     wk0, q0);
      q1 = fmaf(bcast(h1B, k + 1), wk1, q1);
    }
    const float h2A = fmaxf(c0 + c1, 0.0f);
    const float h2B = fmaxf(q0 + q1, 0.0f);

    if (POOL) {
      {
        const int g = batch[nA];             // scalar
        if (g != curg) {
          if (curg >= 0) atomicAdd(&sums[curg * FEAT + lane], gacc);
          curg = g; gacc = 0.0f;
        }
        gacc += h2A;
      }
      if (hasB) {
        const int g = batch[nB];
        if (g != curg) {
          if (curg >= 0) atomicAdd(&sums[curg * FEAT + lane], gacc);
          curg = g; gacc = 0.0f;
        }
        gacc += h2B;
      }
    } else {
      hout[(size_t)nA * FEAT + lane] = h2A;
      if (hasB) hout[(size_t)nB * FEAT + lane] = h2B;
    }
  }
  if (POOL && curg >= 0) atomicAdd(&sums[curg * FEAT + lane], gacc);
}

// ---------------------------------------------------------------------------
// out[g] = dot(sums[g,:], fcW) / cnt[g] + fcb; cnt via binary search on the
// sorted batch array.
// ---------------------------------------------------------------------------
__device__ __forceinline__ int lower_bound_dev(const int* __restrict__ a,
                                               int n, int key) {
  int lo = 0, hi = n;
  while (lo < hi) {
    const int mid = (lo + hi) >> 1;
    if (a[mid] < key) lo = mid + 1; else hi = mid;
  }
  return lo;
}

__global__ void finish_kernel(const float* __restrict__ sums,
                              const int* __restrict__ batch,
                              const float* __restrict__ fcW,
                              const float* __restrict__ fcb,
                              float* __restrict__ out) {
  const int g = blockIdx.x;
  const int lane = threadIdx.x;

  int cnt = 0;
  if (lane == 0) {
    const int lo = lower_bound_dev(batch, N_NODES, g);
    const int hi = lower_bound_dev(batch, N_NODES, g + 1);
    cnt = hi - lo;
  }
  cnt = __shfl(cnt, 0);

  float v = sums[g * FEAT + lane] * fcW[lane];
#pragma unroll
  for (int off = 32; off > 0; off >>= 1) v += __shfl_down(v, off);
  if (lane == 0) out[g] = v / fmaxf((float)cnt, 1.0f) + fcb[0];
}

extern "C" void kernel_launch(void* const* d_in, const int* in_sizes, int n_in,
                              void* d_out, int out_size, void* d_ws, size_t ws_size,
                              hipStream_t stream) {
  const float* x     = (const float*)d_in[0];
  const int*   ei    = (const int*)d_in[1];
  const int*   batch = (const int*)d_in[2];
  const float* W1_0  = (const float*)d_in[3];
  const float* b1_0  = (const float*)d_in[4];
  const float* W2_0  = (const float*)d_in[5];
  const float* b2_0  = (const float*)d_in[6];
  const float* W1_1  = (const float*)d_in[7];
  const float* b1_1  = (const float*)d_in[8];
  const float* W2_1  = (const float*)d_in[9];
  const float* b2_1  = (const float*)d_in[10];
  const float* fcW   = (const float*)d_in[11];
  const float* fcb   = (const float*)d_in[12];
  float* out = (float*)d_out;

  const int* src = ei;            // edge_index[0]
  const int* dst = ei + N_EDGES;  // edge_index[1]

  // workspace layout: [deg | sums | slots16 | slots_ovf | h1]
  int*   deg       = (int*)d_ws;                            // N_NODES
  float* sums      = (float*)(deg + N_NODES);               // N_GRAPHS*FEAT
  int*   slots16   = (int*)(sums + N_GRAPHS * FEAT);        // N_NODES*16
  int*   slots_ovf = slots16 + (size_t)N_NODES * SLOT_MAIN; // N_NODES*32
  float* h1        = (float*)(slots_ovf + (size_t)N_NODES * SLOT_OVF); // N_NODES*FEAT

  // zero deg + sums + slots16 in one contiguous memset
  hipMemsetAsync(deg, 0,
                 (size_t)(N_NODES + N_GRAPHS * FEAT + N_NODES * SLOT_MAIN) * sizeof(int),
                 stream);

  hist_place_kernel<<<NRANGE * 256, 256, 0, stream>>>(src, dst, deg, slots16, slots_ovf);

  gin_layer_kernel<false><<<2048, 256, 0, stream>>>(x, deg, slots16, slots_ovf,
                                                    W1_0, b1_0, W2_0, b2_0,
                                                    h1, nullptr, nullptr);
  gin_layer_kernel<true><<<2048, 256, 0, stream>>>(h1, deg, slots16, slots_ovf,
                                                   W1_1, b1_1, W2_1, b2_1,
                                                   nullptr, batch, sums);

  finish_kernel<<<N_GRAPHS, 64, 0, stream>>>(sums, batch, fcW, fcb, out);
}